// Round 1
// baseline (522.616 us; speedup 1.0000x reference)
//
#include <hip/hip_runtime.h>

// GRU (reset_after, inference) fused with dense head.
// B=1024 rows, T=512 steps, F=16 features, H=64 hidden.
// ONE WAVE PER ROW (64 threads/block): lane j owns hidden unit j and keeps
// the full U column triple (192 regs) + W fragment (48 regs) in registers.
// h[k] is broadcast via v_readlane (SGPR operand of the FMAs).
// No cross-wave combine, no per-step barrier — the 512-step loop is pure
// VALU issue: ~240 FMA + 64 readlane per step.
// x row staged once into LDS (32 KB), read back as uniform-address
// (broadcast) ds_read_b128 at loop top, consumed after the k-loop so the
// LDS latency hides under ~256 independent FMAs.

#define T_ 512
#define F_ 16
#define H_ 64

__device__ __forceinline__ float sigm(float a) {
    return 1.0f / (1.0f + __expf(-a));
}
__device__ __forceinline__ float tanh_fast(float a) {
    // tanh(a) = 1 - 2/(exp(2a)+1); saturates correctly for large |a|
    return 1.0f - 2.0f / (__expf(2.0f * a) + 1.0f);
}

__global__ __launch_bounds__(64, 1) void gru_fused(
    const float* __restrict__ x, const float* __restrict__ W,
    const float* __restrict__ U, const float* __restrict__ b,
    const float* __restrict__ w1, const float* __restrict__ b1,
    const float* __restrict__ gamma_, const float* __restrict__ beta_,
    const float* __restrict__ mmean, const float* __restrict__ mvar,
    const float* __restrict__ w2, const float* __restrict__ b2,
    float* __restrict__ out)
{
    __shared__ float xs[T_ * F_];            // 32 KB: whole x row

    const int j   = threadIdx.x;             // hidden unit, 0..63
    const int row = blockIdx.x;

    // ---- stage x[row] into LDS (coalesced float4, 32 iters) ----
    const float4* xr4 = (const float4*)(x + (size_t)row * (T_ * F_));
    float4* xs4 = (float4*)xs;
    #pragma unroll
    for (int i = 0; i < (T_ * F_ / 4) / 64; ++i)   // 32 iters
        xs4[i * 64 + j] = xr4[i * 64 + j];

    // ---- full U column triple for this lane's hidden unit ----
    float uz[64], ur[64], uh[64];
    #pragma unroll
    for (int k = 0; k < 64; ++k) {
        uz[k] = U[k * 192 + j];
        ur[k] = U[k * 192 + 64 + j];
        uh[k] = U[k * 192 + 128 + j];
    }
    // ---- full W fragment ----
    float wz[16], wr[16], wh[16];
    #pragma unroll
    for (int f = 0; f < 16; ++f) {
        wz[f] = W[f * 192 + j];
        wr[f] = W[f * 192 + 64 + j];
        wh[f] = W[f * 192 + 128 + j];
    }
    // biases (b is [2,192]: b[0]=input bias, b[1]=recurrent bias)
    const float bz  = b[j]       + b[192 + j];   // bi_z + br_z
    const float brr = b[64 + j]  + b[256 + j];   // bi_r + br_r
    const float bxh = b[128 + j];                // bi_h (x-part)
    const float brh = b[320 + j];                // br_h (rec-part)

    __syncthreads();   // xs ready (single wave: effectively a waitcnt)

    float h = 0.0f;
    for (int t = 0; t < T_; ++t) {
        // issue x reads early: uniform address -> LDS broadcast, no conflict;
        // consumed only after the 256-instruction k-loop below.
        const float4 xa = xs4[t * 4 + 0];
        const float4 xb = xs4[t * 4 + 1];
        const float4 xc = xs4[t * 4 + 2];
        const float4 xd = xs4[t * 4 + 3];

        float az = bz, ar = brr, axh = bxh, arh = brh;

        // recurrence: h[k] broadcast via readlane (SGPR operand)
        const int hb = __float_as_int(h);
        #pragma unroll
        for (int k = 0; k < 64; ++k) {
            const float hk = __int_as_float(__builtin_amdgcn_readlane(hb, k));
            az  = fmaf(hk, uz[k], az);
            ar  = fmaf(hk, ur[k], ar);
            arh = fmaf(hk, uh[k], arh);
        }

        // input projection (x values already in registers)
        float xf[16];
        *(float4*)&xf[0]  = xa;
        *(float4*)&xf[4]  = xb;
        *(float4*)&xf[8]  = xc;
        *(float4*)&xf[12] = xd;
        #pragma unroll
        for (int f = 0; f < 16; ++f) {
            az  = fmaf(xf[f], wz[f], az);
            ar  = fmaf(xf[f], wr[f], ar);
            axh = fmaf(xf[f], wh[f], axh);
        }

        // gates
        const float z  = sigm(az);
        const float r  = sigm(ar);
        const float hh = tanh_fast(fmaf(r, arh, axh));
        h = fmaf(z, h - hh, hh);
    }

    // ---- head: y = relu(h @ w1 + b1); BN(inference); out = y @ w2 + b2 ----
    float y = b1[j];
    const int hb2 = __float_as_int(h);
    #pragma unroll
    for (int k = 0; k < H_; ++k) {
        const float hk = __int_as_float(__builtin_amdgcn_readlane(hb2, k));
        y = fmaf(hk, w1[k * H_ + j], y);
    }
    y = fmaxf(y, 0.0f);
    y = fmaf((y - mmean[j]) * rsqrtf(mvar[j] + 1e-3f), gamma_[j], beta_[j]);

    float acc = y * w2[j];
    #pragma unroll
    for (int off = 32; off > 0; off >>= 1)
        acc += __shfl_down(acc, off, 64);
    if (j == 0) out[row] = acc + b2[0];
}

extern "C" void kernel_launch(void* const* d_in, const int* in_sizes, int n_in,
                              void* d_out, int out_size, void* d_ws, size_t ws_size,
                              hipStream_t stream) {
    const float* x      = (const float*)d_in[0];
    const float* W      = (const float*)d_in[1];
    const float* U      = (const float*)d_in[2];
    const float* b      = (const float*)d_in[3];
    const float* w1     = (const float*)d_in[4];
    const float* b1     = (const float*)d_in[5];
    const float* gamma_ = (const float*)d_in[6];
    const float* beta_  = (const float*)d_in[7];
    const float* mmean  = (const float*)d_in[8];
    const float* mvar   = (const float*)d_in[9];
    const float* w2     = (const float*)d_in[10];
    const float* b2     = (const float*)d_in[11];
    float* out = (float*)d_out;

    const int B = in_sizes[0] / (T_ * F_);   // 1024
    gru_fused<<<B, 64, 0, stream>>>(x, W, U, b, w1, b1, gamma_, beta_,
                                    mmean, mvar, w2, b2, out);
}